// Round 5
// baseline (123.359 us; speedup 1.0000x reference)
//
#include <hip/hip_runtime.h>

// Sinkhorn on 8192 independent 64x64 f32 matrices.
// 2 waves per block; block processes TWO matrices (M0, M1). Wave h holds,
// for each matrix: rK[k]=A[lane][32h+k] (row half) and cK[i]=A[32h+i][lane]
// (col half). Per iteration: two independent 32-term partial dots per wave
// (readlane broadcasts, literal indices via rotated u/v), one 2-wave LDS
// exchange per matvec amortized over both matrices. Doubling matrices/wave
// doubles ILP between barriers and halves barrier+LDS cost per matrix.

static constexpr int   kIters = 20;
static constexpr float kEps   = 1e-6f;

__device__ __forceinline__ float RLf(float x, int l) {
    return __int_as_float(__builtin_amdgcn_readlane(__float_as_int(x), l));
}

__global__ __launch_bounds__(128, 3) void sinkhorn64_x2(const float* __restrict__ in,
                                                        float* __restrict__ out) {
    __shared__ float xA0[2][64], xA1[2][64];   // M0 exchange buffers
    __shared__ float xB0[2][64], xB1[2][64];   // M1 exchange buffers
    const int tid  = threadIdx.x;
    const int h    = tid >> 6;               // wave's half (0/1)
    const int lane = tid & 63;
    const int c    = (lane + 32 * h) & 63;   // rotated index (self-inverse)
    const long m0  = (long)blockIdx.x * 2;   // matrices m0, m0+1
    const float* __restrict__ A0 = in  + m0 * 4096;
    const float* __restrict__ A1 = A0 + 4096;
    float* __restrict__ O0       = out + m0 * 4096;
    float* __restrict__ O1       = O0 + 4096;

    // Column halves: cK[i] = A[32h+i][lane]  (coalesced 256B loads)
    float cK0[32], cK1[32];
#pragma unroll
    for (int i = 0; i < 32; ++i) cK0[i] = A0[((32 * h + i) << 6) + lane];
#pragma unroll
    for (int i = 0; i < 32; ++i) cK1[i] = A1[((32 * h + i) << 6) + lane];

    // Row halves: rK[k] = A[lane][32h+k]  (float4 loads, lines hot in L1/L2)
    float rK0[32], rK1[32];
#pragma unroll
    for (int k4 = 0; k4 < 8; ++k4) {
        const float4 f = *reinterpret_cast<const float4*>(A0 + (lane << 6) + 32 * h + (k4 << 2));
        rK0[4 * k4 + 0] = f.x; rK0[4 * k4 + 1] = f.y;
        rK0[4 * k4 + 2] = f.z; rK0[4 * k4 + 3] = f.w;
    }
#pragma unroll
    for (int k4 = 0; k4 < 8; ++k4) {
        const float4 f = *reinterpret_cast<const float4*>(A1 + (lane << 6) + 32 * h + (k4 << 2));
        rK1[4 * k4 + 0] = f.x; rK1[4 * k4 + 1] = f.y;
        rK1[4 * k4 + 2] = f.z; rK1[4 * k4 + 3] = f.w;
    }

    // Row-max partials (per half), exchange, combine plain + rotated.
    float p0 = rK0[0], p1 = rK1[0];
#pragma unroll
    for (int k = 1; k < 32; ++k) { p0 = fmaxf(p0, rK0[k]); p1 = fmaxf(p1, rK1[k]); }
    xA0[h][lane] = p0;
    xB0[h][lane] = p1;
    __syncthreads();
    const float mx0 = fmaxf(p0, xA0[1 - h][lane]);      // max of row `lane`, M0
    const float mr0 = fmaxf(xA0[0][c], xA0[1][c]);      // max of row `c`,   M0
    const float mx1 = fmaxf(p1, xB0[1 - h][lane]);
    const float mr1 = fmaxf(xB0[0][c], xB0[1][c]);

#pragma unroll
    for (int k = 0; k < 32; ++k) {
        rK0[k] = __expf(rK0[k] - mx0);
        rK1[k] = __expf(rK1[k] - mx1);
    }
#pragma unroll
    for (int i = 0; i < 32; ++i) {
        cK0[i] = __expf(cK0[i] - RLf(mr0, i));
        cK1[i] = __expf(cK1[i] - RLf(mr1, i));
    }

    // Rotated scaling vectors: lane holds u_c, v_c for each matrix.
    float u0 = 1.0f, v0 = 1.0f, u1 = 1.0f, v1 = 1.0f;

#pragma unroll 1
    for (int it = 0; it < kIters; ++it) {
        // ---- partial (K v)_{row=lane}: two independent dots ----
        float a0 = 0.f, a1 = 0.f, a2 = 0.f, a3 = 0.f;
        float b0 = 0.f, b1 = 0.f, b2 = 0.f, b3 = 0.f;
#pragma unroll
        for (int k = 0; k < 32; k += 4) {
            a0 = fmaf(RLf(v0, k + 0), rK0[k + 0], a0);
            b0 = fmaf(RLf(v1, k + 0), rK1[k + 0], b0);
            a1 = fmaf(RLf(v0, k + 1), rK0[k + 1], a1);
            b1 = fmaf(RLf(v1, k + 1), rK1[k + 1], b1);
            a2 = fmaf(RLf(v0, k + 2), rK0[k + 2], a2);
            b2 = fmaf(RLf(v1, k + 2), rK1[k + 2], b2);
            a3 = fmaf(RLf(v0, k + 3), rK0[k + 3], a3);
            b3 = fmaf(RLf(v1, k + 3), rK1[k + 3], b3);
        }
        xA1[h][lane] = (a0 + a1) + (a2 + a3);
        xB1[h][lane] = (b0 + b1) + (b2 + b3);
        __syncthreads();
        const float w0 = xA1[0][c] + xA1[1][c];
        u0 = u0 * __builtin_amdgcn_rcpf(fmaf(u0, w0, kEps));
        const float w1 = xB1[0][c] + xB1[1][c];
        u1 = u1 * __builtin_amdgcn_rcpf(fmaf(u1, w1, kEps));

        // ---- partial (K^T u)_{col=lane}: two independent dots ----
        float d0 = 0.f, d1 = 0.f, d2 = 0.f, d3 = 0.f;
        float e0 = 0.f, e1 = 0.f, e2 = 0.f, e3 = 0.f;
#pragma unroll
        for (int i = 0; i < 32; i += 4) {
            d0 = fmaf(RLf(u0, i + 0), cK0[i + 0], d0);
            e0 = fmaf(RLf(u1, i + 0), cK1[i + 0], e0);
            d1 = fmaf(RLf(u0, i + 1), cK0[i + 1], d1);
            e1 = fmaf(RLf(u1, i + 1), cK1[i + 1], e1);
            d2 = fmaf(RLf(u0, i + 2), cK0[i + 2], d2);
            e2 = fmaf(RLf(u1, i + 2), cK1[i + 2], e2);
            d3 = fmaf(RLf(u0, i + 3), cK0[i + 3], d3);
            e3 = fmaf(RLf(u1, i + 3), cK1[i + 3], e3);
        }
        xA0[h][lane] = (d0 + d1) + (d2 + d3);
        xB0[h][lane] = (e0 + e1) + (e2 + e3);
        __syncthreads();
        const float t0 = xA0[0][c] + xA0[1][c];
        v0 = v0 * __builtin_amdgcn_rcpf(fmaf(v0, t0, kEps));
        const float t1 = xB0[0][c] + xB0[1][c];
        v1 = v1 * __builtin_amdgcn_rcpf(fmaf(v1, t1, kEps));
    }

    // Unrotate v (wave 0 holds identity layout).
    xA1[h][lane] = v0;
    xB1[h][lane] = v1;
    __syncthreads();
    const float vf0 = xA1[0][lane];
    const float vf1 = xB1[0][lane];

    // O[32h+i][lane] = u_{32h+i} * K[32h+i][lane] * v_lane  (coalesced)
#pragma unroll
    for (int i = 0; i < 32; ++i) {
        O0[((32 * h + i) << 6) + lane] = RLf(u0, i) * cK0[i] * vf0;
        O1[((32 * h + i) << 6) + lane] = RLf(u1, i) * cK1[i] * vf1;
    }
}

extern "C" void kernel_launch(void* const* d_in, const int* in_sizes, int n_in,
                              void* d_out, int out_size, void* d_ws, size_t ws_size,
                              hipStream_t stream) {
    const float* in = (const float*)d_in[0];
    float* out      = (float*)d_out;
    // 8192 matrices, 2 matrices per 128-thread (2-wave) block.
    sinkhorn64_x2<<<4096, 128, 0, stream>>>(in, out);
}

// Round 6
// 96.466 us; speedup vs baseline: 1.2788x; 1.2788x over previous
//
#include <hip/hip_runtime.h>

// Sinkhorn on 8192 independent 64x64 f32 matrices, FOUR waves per matrix.
// x stays diag(u)*K*diag(v). Wave q (0..3) holds, per 64-row/col index:
//   rK[k] = A[lane][16q+k]  (row `lane`, 16-col slice)  -> partial K*v
//   cK[i] = A[16q+i][lane]  (col `lane`, 16-row slice)  -> partial K^T*u
// u/v stored ROTATED (lane l holds index (l+16q)&63) so all readlane
// indices are literals 0..15. Per matvec: 16 RL + 16 FMA, then a 4-partial
// LDS exchange read as one per-lane float4 (conflict-free), one barrier.
// 32 data VGPRs/wave -> high occupancy; 16-term chains -> short critical path.

static constexpr int   kIters = 20;
static constexpr float kEps   = 1e-6f;

__device__ __forceinline__ float RLf(float x, int l) {
    return __int_as_float(__builtin_amdgcn_readlane(__float_as_int(x), l));
}

__global__ __launch_bounds__(256) void sinkhorn64_q4(const float* __restrict__ in,
                                                     float* __restrict__ out) {
    __shared__ __align__(16) float xbW[64][4];   // K*v   partials [row][wave]
    __shared__ __align__(16) float xbT[64][4];   // K^T*u partials [col][wave]
    __shared__ float vbuf[64];                   // final v unrotate
    const int tid  = threadIdx.x;
    const int q    = tid >> 6;                 // wave's quarter (0..3)
    const int lane = tid & 63;
    const int c    = (lane + 16 * q) & 63;     // rotated index for this lane
    const long m   = blockIdx.x;               // matrix 0..8191
    const float* __restrict__ A = in  + m * 4096;
    float* __restrict__ O       = out + m * 4096;

    // cK[i] = A[16q+i][lane]  (16 coalesced 256B loads)
    float cK[16];
#pragma unroll
    for (int i = 0; i < 16; ++i) cK[i] = A[((16 * q + i) << 6) + lane];

    // rK[k] = A[lane][16q+k]  (4 x float4; lines hot in L1/L2 from cK pass)
    float rK[16];
#pragma unroll
    for (int k4 = 0; k4 < 4; ++k4) {
        const float4 f = *reinterpret_cast<const float4*>(A + (lane << 6) + 16 * q + (k4 << 2));
        rK[4 * k4 + 0] = f.x; rK[4 * k4 + 1] = f.y;
        rK[4 * k4 + 2] = f.z; rK[4 * k4 + 3] = f.w;
    }

    // Row-max: 16-term partial, 4-way exchange (through xbT), combine
    // plain (for rK) and rotated (for cK via literal readlane).
    float pm = rK[0];
#pragma unroll
    for (int k = 1; k < 16; ++k) pm = fmaxf(pm, rK[k]);
    xbT[lane][q] = pm;
    __syncthreads();
    const float4 f4 = *reinterpret_cast<const float4*>(xbT[lane]);
    const float  mx = fmaxf(fmaxf(f4.x, f4.y), fmaxf(f4.z, f4.w));   // row `lane`
    const float4 g4 = *reinterpret_cast<const float4*>(xbT[c]);
    const float mxc = fmaxf(fmaxf(g4.x, g4.y), fmaxf(g4.z, g4.w));   // row `c`

#pragma unroll
    for (int k = 0; k < 16; ++k) rK[k] = __expf(rK[k] - mx);
#pragma unroll
    for (int i = 0; i < 16; ++i) cK[i] = __expf(cK[i] - RLf(mxc, i)); // mx_{16q+i}

    // Rotated scaling vectors: lane holds u_c, v_c.
    float u = 1.0f, v = 1.0f;

#pragma unroll 1
    for (int it = 0; it < kIters; ++it) {
        // ---- partial (K v)_{row=lane} over own 16 columns ----
        float a0 = 0.f, a1 = 0.f, a2 = 0.f, a3 = 0.f;
#pragma unroll
        for (int k = 0; k < 16; k += 4) {
            a0 = fmaf(RLf(v, k + 0), rK[k + 0], a0);   // v_{16q+k} at lane k
            a1 = fmaf(RLf(v, k + 1), rK[k + 1], a1);
            a2 = fmaf(RLf(v, k + 2), rK[k + 2], a2);
            a3 = fmaf(RLf(v, k + 3), rK[k + 3], a3);
        }
        xbW[lane][q] = (a0 + a1) + (a2 + a3);
        __syncthreads();
        const float4 w4 = *reinterpret_cast<const float4*>(xbW[c]);
        const float  w  = (w4.x + w4.y) + (w4.z + w4.w);            // w for row c
        u = u * __builtin_amdgcn_rcpf(fmaf(u, w, kEps));

        // ---- partial (K^T u)_{col=lane} over own 16 rows ----
        float b0 = 0.f, b1 = 0.f, b2 = 0.f, b3 = 0.f;
#pragma unroll
        for (int i = 0; i < 16; i += 4) {
            b0 = fmaf(RLf(u, i + 0), cK[i + 0], b0);   // u_{16q+i} at lane i
            b1 = fmaf(RLf(u, i + 1), cK[i + 1], b1);
            b2 = fmaf(RLf(u, i + 2), cK[i + 2], b2);
            b3 = fmaf(RLf(u, i + 3), cK[i + 3], b3);
        }
        xbT[lane][q] = (b0 + b1) + (b2 + b3);
        __syncthreads();
        const float4 t4 = *reinterpret_cast<const float4*>(xbT[c]);
        const float  t  = (t4.x + t4.y) + (t4.z + t4.w);            // t for col c
        v = v * __builtin_amdgcn_rcpf(fmaf(v, t, kEps));
    }

    // Unrotate v: vbuf[c] = v_c, then read plain layout.
    vbuf[c] = v;
    __syncthreads();
    const float vf = vbuf[lane];

    // O[16q+i][lane] = u_{16q+i} * K[16q+i][lane] * v_lane  (coalesced)
#pragma unroll
    for (int i = 0; i < 16; ++i) {
        O[((16 * q + i) << 6) + lane] = RLf(u, i) * cK[i] * vf;
    }
}

extern "C" void kernel_launch(void* const* d_in, const int* in_sizes, int n_in,
                              void* d_out, int out_size, void* d_ws, size_t ws_size,
                              hipStream_t stream) {
    const float* in = (const float*)d_in[0];
    float* out      = (float*)d_out;
    // One matrix per 256-thread (4-wave) block.
    sinkhorn64_q4<<<8192, 256, 0, stream>>>(in, out);
}